// Round 1
// 351.698 us; speedup vs baseline: 1.0257x; 1.0257x over previous
//
#include <hip/hip_runtime.h>
#include <math.h>

// Problem constants (fixed by the reference):
//   x: [B=16, C=256, H=128, W=128] fp32
//   w: [1, 2, 7, 7] fp32
//   out: [16, 1, 128, 128] fp32 = sigmoid(conv2d(concat(mean_c(x), max_c(x)), w, pad=3))
// The fft2->ifft2 round trip is the identity on the real part -> skipped.

#define BB 16
#define CC 256
#define HH 128
#define WW 128
#define HW (HH * WW)          // 16384
#define CHW (CC * HW)         // 4194304
#define HW4 (HW / 4)          // 4096 float4 groups per plane
#define NPOS (BB * HW)        // 262144 output pixels
#define NG (BB * HW4)         // 65536 float4 groups total

typedef float floatx4 __attribute__((ext_vector_type(4)));

// ---------------------------------------------------------------------------
// Kernel 1: per-pixel channel mean + max over C=256.
// Grid: 1024 blocks x 512 threads. Block = 64 float4-groups (lanes) x 8
// channel-eighths (waves). Each thread: 32 strided 16B loads; each wave-load
// is 64 lanes x 16 B = 1 KiB contiguous -> fully coalesced. Non-temporal:
// x is streamed once (256 MiB) and must not evict the s intermediate.
// Tail: sum-reduce and max-reduce split across two warps (was serial in one).
// ---------------------------------------------------------------------------
__global__ __launch_bounds__(512) void reduce_mean_max_kernel(
    const float* __restrict__ x, float* __restrict__ s) {
  const int tid  = threadIdx.x;
  const int lane = tid & 63;        // float4 group within block
  const int q    = tid >> 6;        // channel eighth 0..7 (wave id)
  const int g    = blockIdx.x * 64 + lane;  // global float4 group
  const int b    = g >> 12;         // g / 4096
  const int off  = g & 4095;        // float4 index within the HxW plane

  const floatx4* p =
      (const floatx4*)(x + (size_t)b * CHW) + off + (size_t)(q * 32) * HW4;

  floatx4 sum = (floatx4)(0.f);
  floatx4 mx  = (floatx4)(-INFINITY);

#pragma unroll 8
  for (int i = 0; i < 32; ++i) {
    floatx4 v = __builtin_nontemporal_load(p + (size_t)i * HW4);
    sum += v;
    mx.x = fmaxf(mx.x, v.x); mx.y = fmaxf(mx.y, v.y);
    mx.z = fmaxf(mx.z, v.z); mx.w = fmaxf(mx.w, v.w);
  }

  __shared__ floatx4 s_sum[8][64];
  __shared__ floatx4 s_max[8][64];
  s_sum[q][lane] = sum;
  s_max[q][lane] = mx;
  __syncthreads();

  // Threads 0-63: sum chain. Threads 64-127: max chain. Parallel, not serial.
  if (tid < 128) {
    const int l   = tid & 63;
    const int gg  = blockIdx.x * 64 + l;
    const int bb  = gg >> 12;
    const int of2 = gg & 4095;
    if (tid < 64) {
      floatx4 ts = s_sum[0][l];
#pragma unroll
      for (int qq = 1; qq < 8; ++qq) ts += s_sum[qq][l];
      ts *= (1.0f / (float)CC);
      ((floatx4*)(s + (size_t)bb * 2 * HW))[of2] = ts;          // ch 0: avg
    } else {
      floatx4 tm = s_max[0][l];
#pragma unroll
      for (int qq = 1; qq < 8; ++qq) {
        floatx4 m = s_max[qq][l];
        tm.x = fmaxf(tm.x, m.x); tm.y = fmaxf(tm.y, m.y);
        tm.z = fmaxf(tm.z, m.z); tm.w = fmaxf(tm.w, m.w);
      }
      ((floatx4*)(s + (size_t)bb * 2 * HW + HW))[of2] = tm;     // ch 1: max
    }
  }
}

// ---------------------------------------------------------------------------
// Kernel 2: 2->1 channel 7x7 'same' cross-correlation (pad 3) + sigmoid.
// Register-blocked + LDS-tiled: 256 blocks (one per CU), block = (b, 8-row
// band). Stage 2ch x 14 rows x 136 cols (zero-padded) of s in LDS (15.2 KB),
// then each thread computes a 4-tall output column with sliding-window
// reuse: 2*7*10 = 35 LDS reads per 4 outputs (vs 98 branchy L1 loads/output
// before). LDS reads are stride-1 across the wave -> conflict-free; stores
// coalesced along x.
// ---------------------------------------------------------------------------
#define BAND 8
#define TR   14      // BAND + 6 halo rows
#define LDW  136     // 3 + 128 + 3 zero pad, rounded up

__global__ __launch_bounds__(256) void conv_sigmoid_kernel(
    const float* __restrict__ s, const float* __restrict__ w,
    float* __restrict__ out) {
  __shared__ float tile[2][TR][LDW];
  __shared__ float wf[2 * 49];

  const int tid  = threadIdx.x;
  const int blk  = blockIdx.x;      // 0..255
  const int b    = blk >> 4;        // batch
  const int band = blk & 15;        // 8-row band within the plane
  const int y0   = band * BAND;

  if (tid < 2 * 49) wf[tid] = w[tid];

  // Fill the padded LDS band: 28 (ch,row) jobs across 8 groups of 32 threads.
  const int grp = tid >> 5;         // 0..7
  const int l32 = tid & 31;
  for (int job = grp; job < 2 * TR; job += 8) {
    const int ci = (job >= TR) ? 1 : 0;
    const int r  = ci ? (job - TR) : job;
    const int yy = y0 + r - 3;
    const bool inrow = (yy >= 0 && yy < HH);
    const float* src = s + ((size_t)b * 2 + ci) * HW + (size_t)yy * WW;
    float* dst = tile[ci][r];
    for (int c = l32; c < LDW; c += 32) {
      const int xx = c - 3;
      dst[c] = (inrow && xx >= 0 && xx < WW) ? src[xx] : 0.f;
    }
  }
  __syncthreads();

  const int xpo  = tid & 127;       // output column
  const int ysub = (tid >> 7) * 4;  // 0 or 4: 4-row output sub-band

  float acc0 = 0.f, acc1 = 0.f, acc2 = 0.f, acc3 = 0.f;
#pragma unroll
  for (int ci = 0; ci < 2; ++ci) {
#pragma unroll
    for (int kw = 0; kw < 7; ++kw) {
      float v[10];
#pragma unroll
      for (int r = 0; r < 10; ++r) v[r] = tile[ci][ysub + r][xpo + kw];
      const float* wc = wf + ci * 49 + kw;
#pragma unroll
      for (int kh = 0; kh < 7; ++kh) {
        const float wv = wc[kh * 7];
        acc0 = fmaf(v[kh],     wv, acc0);
        acc1 = fmaf(v[kh + 1], wv, acc1);
        acc2 = fmaf(v[kh + 2], wv, acc2);
        acc3 = fmaf(v[kh + 3], wv, acc3);
      }
    }
  }

  float* ob = out + (size_t)b * HW + (size_t)(y0 + ysub) * WW + xpo;
  ob[0]      = 1.0f / (1.0f + expf(-acc0));
  ob[WW]     = 1.0f / (1.0f + expf(-acc1));
  ob[2 * WW] = 1.0f / (1.0f + expf(-acc2));
  ob[3 * WW] = 1.0f / (1.0f + expf(-acc3));
}

extern "C" void kernel_launch(void* const* d_in, const int* in_sizes, int n_in,
                              void* d_out, int out_size, void* d_ws, size_t ws_size,
                              hipStream_t stream) {
  const float* x = (const float*)d_in[0];
  const float* w = (const float*)d_in[1];
  float* out = (float*)d_out;
  float* s   = (float*)d_ws;  // [16][2][128][128] fp32 = 2 MB scratch

  // Kernel 1: 65536 float4 groups / 64 per block = 1024 blocks x 512 threads.
  reduce_mean_max_kernel<<<NG / 64, 512, 0, stream>>>(x, s);

  // Kernel 2: 16 batches x 16 bands = 256 blocks x 256 threads.
  conv_sigmoid_kernel<<<BB * (HH / BAND), 256, 0, stream>>>(s, w, out);
}